// Round 1
// baseline (211.507 us; speedup 1.0000x reference)
//
#include <hip/hip_runtime.h>

typedef unsigned short u16;
typedef __attribute__((ext_vector_type(8))) short s8v;
typedef __attribute__((ext_vector_type(4))) float f4v;

#define BB 4
#define SS 1024
#define EE 768
#define HH 12
#define DD 64

static __device__ __forceinline__ u16 f2bf(float x){
  unsigned int u = __float_as_uint(x);
  u += 0x7fffu + ((u >> 16) & 1u);
  return (u16)(u >> 16);
}

// ---------------- position bias (also output 1) -----------------
__global__ __launch_bounds__(256) void pb_kernel(const float* __restrict__ rel_embed,
                                                 float* __restrict__ pb){
  int id = blockIdx.x * 256 + threadIdx.x;     // over S*S
  int i = id >> 10, j = id & (SS - 1);
  int rel = j - i;
  int bucket = (rel > 0) ? 160 : 0;
  int a = rel < 0 ? -rel : rel;
  int idx;
  if (a < 80) {
    idx = a;
  } else {
    float t = logf((float)a / 80.0f);
    t = t / 2.302585092994046f * 80.0f;
    int lg = (int)(80.0f + t);
    idx = lg < 159 ? lg : 159;
  }
  idx += bucket;
  #pragma unroll
  for (int h = 0; h < HH; h++)
    pb[(size_t)h * (SS * SS) + id] = rel_embed[idx * HH + h];
}

// ---------------- gate -----------------
__global__ __launch_bounds__(256) void gate_kernel(const float* __restrict__ hs,
                                                   const float* __restrict__ gru_w,
                                                   const float* __restrict__ gru_b,
                                                   const float* __restrict__ gru_c,
                                                   float* __restrict__ gate){
  int id = blockIdx.x * 256 + threadIdx.x;     // over B*H*S
  int s = id & (SS - 1);
  int bh = id >> 10;
  int h = bh % HH, b = bh / HH;
  const float* x = hs + ((size_t)(b * SS + s) * EE + h * DD);
  float p[8];
  #pragma unroll
  for (int e = 0; e < 8; e++) p[e] = gru_b[e];
  for (int d = 0; d < DD; d++){
    float xv = x[d];
    #pragma unroll
    for (int e = 0; e < 8; e++) p[e] += xv * gru_w[e * DD + d];
  }
  float s0 = p[0] + p[1] + p[2] + p[3];
  float s1 = p[4] + p[5] + p[6] + p[7];
  float ga = 1.f / (1.f + __expf(-s0));
  float gb = 1.f / (1.f + __expf(-s1));
  gate[id] = ga * (gb * gru_c[h] - 1.0f) + 2.0f;
}

// ---------------- NT GEMM: C[4096][768] = A[4096][768] * B[768][768]^T, bf16 MFMA ----------------
template<bool A_F32, bool OUT_BF16>
__global__ __launch_bounds__(256) void gemm_nt(const void* __restrict__ Ap,
                                               const float* __restrict__ Bw,
                                               const float* __restrict__ bias,
                                               void* __restrict__ Cp,
                                               float scale){
  __shared__ __align__(16) u16 a_s[128][40];
  __shared__ __align__(16) u16 b_s[128][40];
  const int t = threadIdx.x;
  const int wave = t >> 6, lane = t & 63;
  const int lr = lane & 15, lg = lane >> 4;
  const int m0 = blockIdx.x * 128, n0 = blockIdx.y * 128;
  const int wm = (wave >> 1) * 64, wn = (wave & 1) * 64;
  const int sr = t >> 1, sc = (t & 1) * 16;

  const f4v zero = {0.f, 0.f, 0.f, 0.f};
  f4v acc[4][4];
  #pragma unroll
  for (int i = 0; i < 4; i++)
    #pragma unroll
    for (int j = 0; j < 4; j++) acc[i][j] = zero;

  for (int k0 = 0; k0 < EE; k0 += 32){
    s8v wa0, wa1, wb0, wb1;
    if (A_F32){
      const float* src = (const float*)Ap + (size_t)(m0 + sr) * EE + k0 + sc;
      f4v v0 = *(const f4v*)(src + 0), v1 = *(const f4v*)(src + 4),
          v2 = *(const f4v*)(src + 8), v3 = *(const f4v*)(src + 12);
      #pragma unroll
      for (int ii = 0; ii < 4; ii++){
        wa0[ii] = (short)f2bf(v0[ii]); wa0[4 + ii] = (short)f2bf(v1[ii]);
        wa1[ii] = (short)f2bf(v2[ii]); wa1[4 + ii] = (short)f2bf(v3[ii]);
      }
    } else {
      const u16* src = (const u16*)Ap + (size_t)(m0 + sr) * EE + k0 + sc;
      wa0 = *(const s8v*)src; wa1 = *(const s8v*)(src + 8);
    }
    {
      const float* src = Bw + (size_t)(n0 + sr) * EE + k0 + sc;
      f4v v0 = *(const f4v*)(src + 0), v1 = *(const f4v*)(src + 4),
          v2 = *(const f4v*)(src + 8), v3 = *(const f4v*)(src + 12);
      #pragma unroll
      for (int ii = 0; ii < 4; ii++){
        wb0[ii] = (short)f2bf(v0[ii]); wb0[4 + ii] = (short)f2bf(v1[ii]);
        wb1[ii] = (short)f2bf(v2[ii]); wb1[4 + ii] = (short)f2bf(v3[ii]);
      }
    }
    *(s8v*)&a_s[sr][sc] = wa0; *(s8v*)&a_s[sr][sc + 8] = wa1;
    *(s8v*)&b_s[sr][sc] = wb0; *(s8v*)&b_s[sr][sc + 8] = wb1;
    __syncthreads();
    s8v af[4], bfr[4];
    #pragma unroll
    for (int i = 0; i < 4; i++){
      af[i]  = *(const s8v*)&a_s[wm + i * 16 + lr][lg * 8];
      bfr[i] = *(const s8v*)&b_s[wn + i * 16 + lr][lg * 8];
    }
    #pragma unroll
    for (int i = 0; i < 4; i++)
      #pragma unroll
      for (int j = 0; j < 4; j++)
        acc[i][j] = __builtin_amdgcn_mfma_f32_16x16x32_bf16(af[i], bfr[j], acc[i][j], 0, 0, 0);
    __syncthreads();
  }

  #pragma unroll
  for (int i = 0; i < 4; i++){
    const int row = m0 + wm + i * 16 + lg * 4;
    #pragma unroll
    for (int j = 0; j < 4; j++){
      const int col = n0 + wn + j * 16 + lr;
      const float bv = bias[col];
      #pragma unroll
      for (int r = 0; r < 4; r++){
        float val = (acc[i][j][r] + bv) * scale;
        if (OUT_BF16) ((u16*)Cp)[(size_t)(row + r) * EE + col] = f2bf(val);
        else          ((float*)Cp)[(size_t)(row + r) * EE + col] = val;
      }
    }
  }
}

// ---------------- V transpose: v[b*S+s][h*64+d] -> vt[(b*H+h)*64+d][s] ----------------
__global__ __launch_bounds__(256) void vt_kernel(const u16* __restrict__ v,
                                                 u16* __restrict__ vt){
  __shared__ __align__(16) u16 tile[64][72];
  const int t = threadIdx.x;
  const int s0 = blockIdx.x * 64;
  const int bh = blockIdx.y;
  const int b = bh / HH, h = bh % HH;
  {
    const int r = t >> 2, c = (t & 3) * 16;
    const u16* src = v + (size_t)(b * SS + s0 + r) * EE + h * DD + c;
    *(s8v*)&tile[r][c]     = *(const s8v*)src;
    *(s8v*)&tile[r][c + 8] = *(const s8v*)(src + 8);
  }
  __syncthreads();
  {
    const int d = t >> 2, sc = (t & 3) * 16;
    s8v o0, o1;
    #pragma unroll
    for (int i = 0; i < 8; i++){
      o0[i] = (short)tile[sc + i][d];
      o1[i] = (short)tile[sc + 8 + i][d];
    }
    u16* dst = vt + (size_t)(bh * DD + d) * SS + s0 + sc;
    *(s8v*)dst       = o0;
    *(s8v*)(dst + 8) = o1;
  }
}

// ---------------- flash attention with gated bias ----------------
__global__ __launch_bounds__(256) void attn_kernel(const u16* __restrict__ qb,
                                                   const u16* __restrict__ kb,
                                                   const u16* __restrict__ vtb,
                                                   const float* __restrict__ gate,
                                                   const float* __restrict__ pb,
                                                   u16* __restrict__ ctx){
  __shared__ __align__(16) u16 q_s[64][72];
  __shared__ __align__(16) u16 k_s[64][72];
  __shared__ __align__(16) u16 v_s[64][72];
  __shared__ __align__(16) u16 p_s[4][16][72];
  const int t = threadIdx.x, wave = t >> 6, lane = t & 63;
  const int lr = lane & 15, lg = lane >> 4;
  const int q0 = blockIdx.x * 64;
  const int h = blockIdx.y, b = blockIdx.z;
  const int sr = t >> 2, scc = (t & 3) * 16;
  {
    const u16* src = qb + (size_t)(b * SS + q0 + sr) * EE + h * DD + scc;
    *(s8v*)&q_s[sr][scc]     = *(const s8v*)src;
    *(s8v*)&q_s[sr][scc + 8] = *(const s8v*)(src + 8);
  }
  __syncthreads();
  const s8v qf0 = *(const s8v*)&q_s[wave * 16 + lr][lg * 8];
  const s8v qf1 = *(const s8v*)&q_s[wave * 16 + lr][32 + lg * 8];
  float gt[4];
  #pragma unroll
  for (int r = 0; r < 4; r++)
    gt[r] = gate[(size_t)(b * HH + h) * SS + q0 + wave * 16 + lg * 4 + r];

  const f4v zero = {0.f, 0.f, 0.f, 0.f};
  f4v o[4];
  float m[4], l[4];
  #pragma unroll
  for (int d = 0; d < 4; d++) o[d] = zero;
  #pragma unroll
  for (int r = 0; r < 4; r++){ m[r] = -1e30f; l[r] = 0.f; }

  const float* pbh = pb + (size_t)h * SS * SS;
  const u16* kbase = kb + (size_t)b * SS * EE + h * DD;
  const u16* vbase = vtb + (size_t)(b * HH + h) * DD * SS;
  const int qrow = q0 + wave * 16 + lg * 4;

  for (int kt = 0; kt < 16; kt++){
    const int k0 = kt * 64;
    __syncthreads();
    {
      const u16* ks = kbase + (size_t)(k0 + sr) * EE + scc;
      *(s8v*)&k_s[sr][scc]     = *(const s8v*)ks;
      *(s8v*)&k_s[sr][scc + 8] = *(const s8v*)(ks + 8);
      const u16* vs = vbase + (size_t)sr * SS + k0 + scc;
      *(s8v*)&v_s[sr][scc]     = *(const s8v*)vs;
      *(s8v*)&v_s[sr][scc + 8] = *(const s8v*)(vs + 8);
    }
    __syncthreads();
    f4v sf[4];
    #pragma unroll
    for (int n = 0; n < 4; n++){
      const s8v kf0 = *(const s8v*)&k_s[n * 16 + lr][lg * 8];
      const s8v kf1 = *(const s8v*)&k_s[n * 16 + lr][32 + lg * 8];
      f4v z = zero;
      z = __builtin_amdgcn_mfma_f32_16x16x32_bf16(qf0, kf0, z, 0, 0, 0);
      z = __builtin_amdgcn_mfma_f32_16x16x32_bf16(qf1, kf1, z, 0, 0, 0);
      sf[n] = z;
    }
    #pragma unroll
    for (int n = 0; n < 4; n++)
      #pragma unroll
      for (int r = 0; r < 4; r++)
        sf[n][r] += gt[r] * pbh[(size_t)(qrow + r) * SS + k0 + n * 16 + lr];

    float mx[4], scl[4], rs[4];
    #pragma unroll
    for (int r = 0; r < 4; r++)
      mx[r] = fmaxf(fmaxf(sf[0][r], sf[1][r]), fmaxf(sf[2][r], sf[3][r]));
    #pragma unroll
    for (int off = 1; off < 16; off <<= 1)
      #pragma unroll
      for (int r = 0; r < 4; r++)
        mx[r] = fmaxf(mx[r], __shfl_xor(mx[r], off));
    #pragma unroll
    for (int r = 0; r < 4; r++){
      float nm = fmaxf(m[r], mx[r]);
      scl[r] = __expf(m[r] - nm);
      m[r] = nm;
      rs[r] = 0.f;
    }
    #pragma unroll
    for (int n = 0; n < 4; n++)
      #pragma unroll
      for (int r = 0; r < 4; r++){
        float p = __expf(sf[n][r] - m[r]);
        sf[n][r] = p;
        rs[r] += p;
      }
    #pragma unroll
    for (int off = 1; off < 16; off <<= 1)
      #pragma unroll
      for (int r = 0; r < 4; r++)
        rs[r] += __shfl_xor(rs[r], off);
    #pragma unroll
    for (int r = 0; r < 4; r++)
      l[r] = l[r] * scl[r] + rs[r];
    #pragma unroll
    for (int d = 0; d < 4; d++)
      #pragma unroll
      for (int r = 0; r < 4; r++)
        o[d][r] *= scl[r];
    #pragma unroll
    for (int n = 0; n < 4; n++)
      #pragma unroll
      for (int r = 0; r < 4; r++)
        p_s[wave][lg * 4 + r][n * 16 + lr] = f2bf(sf[n][r]);
    __syncthreads();
    const s8v pf0 = *(const s8v*)&p_s[wave][lr][lg * 8];
    const s8v pf1 = *(const s8v*)&p_s[wave][lr][32 + lg * 8];
    #pragma unroll
    for (int d = 0; d < 4; d++){
      const s8v vf0 = *(const s8v*)&v_s[d * 16 + lr][lg * 8];
      const s8v vf1 = *(const s8v*)&v_s[d * 16 + lr][32 + lg * 8];
      o[d] = __builtin_amdgcn_mfma_f32_16x16x32_bf16(pf0, vf0, o[d], 0, 0, 0);
      o[d] = __builtin_amdgcn_mfma_f32_16x16x32_bf16(pf1, vf1, o[d], 0, 0, 0);
    }
  }
  #pragma unroll
  for (int d = 0; d < 4; d++)
    #pragma unroll
    for (int r = 0; r < 4; r++){
      float val = o[d][r] / l[r];
      ctx[(size_t)(b * SS + qrow + r) * EE + h * DD + d * 16 + lr] = f2bf(val);
    }
}

extern "C" void kernel_launch(void* const* d_in, const int* in_sizes, int n_in,
                              void* d_out, int out_size, void* d_ws, size_t ws_size,
                              hipStream_t stream){
  const float* hs    = (const float*)d_in[0];
  const float* q_w   = (const float*)d_in[1];
  const float* q_b   = (const float*)d_in[2];
  const float* k_w   = (const float*)d_in[3];
  const float* k_b   = (const float*)d_in[4];
  const float* v_w   = (const float*)d_in[5];
  const float* v_b   = (const float*)d_in[6];
  const float* o_w   = (const float*)d_in[7];
  const float* o_b   = (const float*)d_in[8];
  const float* gru_c = (const float*)d_in[9];
  const float* gru_w = (const float*)d_in[10];
  const float* gru_b = (const float*)d_in[11];
  const float* rel   = (const float*)d_in[12];

  float* out0 = (float*)d_out;
  float* pb   = out0 + (size_t)BB * SS * EE;       // 3,145,728 floats in

  char* w = (char*)d_ws;
  u16* qbuf = (u16*)w;  w += (size_t)BB * SS * EE * 2;
  u16* kbuf = (u16*)w;  w += (size_t)BB * SS * EE * 2;
  u16* vbuf = (u16*)w;  w += (size_t)BB * SS * EE * 2;
  u16* vtb  = (u16*)w;  w += (size_t)BB * SS * EE * 2;
  u16* ctx  = (u16*)w;  w += (size_t)BB * SS * EE * 2;
  float* gate = (float*)w;

  pb_kernel<<<(SS * SS) / 256, 256, 0, stream>>>(rel, pb);
  gate_kernel<<<(BB * HH * SS) / 256, 256, 0, stream>>>(hs, gru_w, gru_b, gru_c, gate);
  gemm_nt<true, true><<<dim3(32, 6), 256, 0, stream>>>(hs, q_w, q_b, qbuf, 0.125f);
  gemm_nt<true, true><<<dim3(32, 6), 256, 0, stream>>>(hs, k_w, k_b, kbuf, 1.0f);
  gemm_nt<true, true><<<dim3(32, 6), 256, 0, stream>>>(hs, v_w, v_b, vbuf, 1.0f);
  vt_kernel<<<dim3(SS / 64, BB * HH), 256, 0, stream>>>(vbuf, vtb);
  attn_kernel<<<dim3(SS / 64, HH, BB), 256, 0, stream>>>(qbuf, kbuf, vtb, gate, pb, ctx);
  gemm_nt<false, false><<<dim3(32, 6), 256, 0, stream>>>(ctx, o_w, o_b, out0, 1.0f);
}

// Round 2
// 138.959 us; speedup vs baseline: 1.5221x; 1.5221x over previous
//
#include <hip/hip_runtime.h>

typedef unsigned short u16;
typedef __attribute__((ext_vector_type(8))) short s8v;
typedef __attribute__((ext_vector_type(4))) float f4v;

#define BB 4
#define SS 1024
#define EE 768
#define HH 12
#define DD 64

#define NHS (BB * SS * EE)           // 3145728
#define NW  (EE * EE)                // 589824

static __device__ __forceinline__ u16 f2bf(float x){
  unsigned int u = __float_as_uint(x);
  u += 0x7fffu + ((u >> 16) & 1u);
  return (u16)(u >> 16);
}

// ---------------- fused f32->bf16 conversion: hs, q_w, k_w, v_w, out_w ----------------
__global__ __launch_bounds__(256) void cvt_kernel(const float* __restrict__ hs,
                                                  const float* __restrict__ qw,
                                                  const float* __restrict__ kw,
                                                  const float* __restrict__ vw,
                                                  const float* __restrict__ ow,
                                                  u16* __restrict__ dst){
  size_t e = ((size_t)blockIdx.x * 256 + threadIdx.x) * 8;
  const float* src;
  if      (e < (size_t)NHS)            src = hs + e;
  else if (e < (size_t)NHS + NW)       src = qw + (e - NHS);
  else if (e < (size_t)NHS + 2 * NW)   src = kw + (e - NHS - NW);
  else if (e < (size_t)NHS + 3 * NW)   src = vw + (e - NHS - 2 * (size_t)NW);
  else                                 src = ow + (e - NHS - 3 * (size_t)NW);
  f4v v0 = *(const f4v*)src, v1 = *(const f4v*)(src + 4);
  s8v o;
  #pragma unroll
  for (int i = 0; i < 4; i++){ o[i] = (short)f2bf(v0[i]); o[4 + i] = (short)f2bf(v1[i]); }
  *(s8v*)(dst + e) = o;
}

// ---------------- 1-D bias table: tbl[h][rel+1023], padded stride 2048 ----------------
__global__ __launch_bounds__(256) void tbl_kernel(const float* __restrict__ rel_embed,
                                                  float* __restrict__ tbl){
  int id = blockIdx.x * 256 + threadIdx.x;   // over 12*2048
  int h = id >> 11, r = id & 2047;
  float v = 0.f;
  if (r < 2047){
    int rel = r - 1023;
    int bucket = (rel > 0) ? 160 : 0;
    int a = rel < 0 ? -rel : rel;
    int idx;
    if (a < 80) idx = a;
    else {
      float t = logf((float)a / 80.0f);
      t = t / 2.302585092994046f * 80.0f;
      int lg = (int)(80.0f + t);
      idx = lg < 159 ? lg : 159;
    }
    v = rel_embed[(idx + bucket) * HH + h];
  }
  tbl[id] = v;
}

// ---------------- position bias (output 1) from table ----------------
__global__ __launch_bounds__(256) void pb_kernel(const float* __restrict__ tbl,
                                                 float* __restrict__ pb){
  int id = blockIdx.x * 256 + threadIdx.x;    // over S*S/4
  int i = id >> 8, j = (id & 255) * 4;
  int base = j - i + 1023;
  #pragma unroll
  for (int h = 0; h < HH; h++){
    const float* th = tbl + h * 2048;
    f4v v;
    #pragma unroll
    for (int jj = 0; jj < 4; jj++) v[jj] = th[base + jj];
    *(f4v*)&pb[(size_t)h * (SS * SS) + (size_t)i * SS + j] = v;
  }
}

// ---------------- gate: two 64-length dots with pre-summed weights ----------------
__global__ __launch_bounds__(256) void gate_kernel(const float* __restrict__ hs,
                                                   const float* __restrict__ gru_w,
                                                   const float* __restrict__ gru_b,
                                                   const float* __restrict__ gru_c,
                                                   float* __restrict__ gate){
  int wid = blockIdx.x * 4 + (threadIdx.x >> 6);  // over B*H*S rows
  int lane = threadIdx.x & 63;
  int s = wid & (SS - 1);
  int bh = wid >> 10;
  int h = bh % HH, b = bh / HH;
  float x = hs[(size_t)(b * SS + s) * EE + h * DD + lane];
  float w0 = gru_w[lane] + gru_w[64 + lane] + gru_w[128 + lane] + gru_w[192 + lane];
  float w1 = gru_w[256 + lane] + gru_w[320 + lane] + gru_w[384 + lane] + gru_w[448 + lane];
  float y0 = x * w0, y1 = x * w1;
  #pragma unroll
  for (int off = 1; off < 64; off <<= 1){
    y0 += __shfl_xor(y0, off);
    y1 += __shfl_xor(y1, off);
  }
  if (lane == 0){
    float s0 = y0 + gru_b[0] + gru_b[1] + gru_b[2] + gru_b[3];
    float s1 = y1 + gru_b[4] + gru_b[5] + gru_b[6] + gru_b[7];
    float ga = 1.f / (1.f + __expf(-s0));
    float gb = 1.f / (1.f + __expf(-s1));
    gate[wid] = ga * (gb * gru_c[h] - 1.0f) + 2.0f;
  }
}

// ---------------- bf16 NT GEMM body: C[128][128] tile, BK=64 ----------------
template<bool OUT_BF16>
static __device__ __forceinline__ void gemm_body(const u16* __restrict__ A,
                                                 const u16* __restrict__ Bw,
                                                 const float* __restrict__ bias,
                                                 void* __restrict__ Cp,
                                                 float scale, int m0, int n0){
  __shared__ __align__(16) u16 a_s[128][72];
  __shared__ __align__(16) u16 b_s[128][72];
  const int t = threadIdx.x;
  const int wave = t >> 6, lane = t & 63;
  const int lr = lane & 15, lg = lane >> 4;
  const int wm = (wave >> 1) * 64, wn = (wave & 1) * 64;
  const int sr = t >> 1, sc = (t & 1) * 32;

  const f4v zero = {0.f, 0.f, 0.f, 0.f};
  f4v acc[4][4];
  #pragma unroll
  for (int i = 0; i < 4; i++)
    #pragma unroll
    for (int j = 0; j < 4; j++) acc[i][j] = zero;

  for (int k0 = 0; k0 < EE; k0 += 64){
    const u16* sa = A  + (size_t)(m0 + sr) * EE + k0 + sc;
    const u16* sb = Bw + (size_t)(n0 + sr) * EE + k0 + sc;
    s8v a0 = *(const s8v*)(sa +  0), a1 = *(const s8v*)(sa +  8),
        a2 = *(const s8v*)(sa + 16), a3 = *(const s8v*)(sa + 24);
    s8v b0 = *(const s8v*)(sb +  0), b1 = *(const s8v*)(sb +  8),
        b2 = *(const s8v*)(sb + 16), b3 = *(const s8v*)(sb + 24);
    if (k0) __syncthreads();
    *(s8v*)&a_s[sr][sc +  0] = a0; *(s8v*)&a_s[sr][sc +  8] = a1;
    *(s8v*)&a_s[sr][sc + 16] = a2; *(s8v*)&a_s[sr][sc + 24] = a3;
    *(s8v*)&b_s[sr][sc +  0] = b0; *(s8v*)&b_s[sr][sc +  8] = b1;
    *(s8v*)&b_s[sr][sc + 16] = b2; *(s8v*)&b_s[sr][sc + 24] = b3;
    __syncthreads();
    #pragma unroll
    for (int kk = 0; kk < 2; kk++){
      s8v af[4], bf[4];
      #pragma unroll
      for (int i = 0; i < 4; i++){
        af[i] = *(const s8v*)&a_s[wm + i * 16 + lr][kk * 32 + lg * 8];
        bf[i] = *(const s8v*)&b_s[wn + i * 16 + lr][kk * 32 + lg * 8];
      }
      #pragma unroll
      for (int i = 0; i < 4; i++)
        #pragma unroll
        for (int j = 0; j < 4; j++)
          acc[i][j] = __builtin_amdgcn_mfma_f32_16x16x32_bf16(af[i], bf[j], acc[i][j], 0, 0, 0);
    }
  }

  #pragma unroll
  for (int i = 0; i < 4; i++){
    const int row = m0 + wm + i * 16 + lg * 4;
    #pragma unroll
    for (int j = 0; j < 4; j++){
      const int col = n0 + wn + j * 16 + lr;
      const float bv = bias[col];
      #pragma unroll
      for (int r = 0; r < 4; r++){
        float val = (acc[i][j][r] + bv) * scale;
        if (OUT_BF16) ((u16*)Cp)[(size_t)(row + r) * EE + col] = f2bf(val);
        else          ((float*)Cp)[(size_t)(row + r) * EE + col] = val;
      }
    }
  }
}

// fused QKV GEMM: z selects weight/bias/output
__global__ __launch_bounds__(256) void gemm_qkv(const u16* __restrict__ A,
                                                const u16* __restrict__ wqkv,
                                                const float* __restrict__ bq,
                                                const float* __restrict__ bk,
                                                const float* __restrict__ bv,
                                                u16* __restrict__ qo,
                                                u16* __restrict__ ko,
                                                u16* __restrict__ vo){
  const int z = blockIdx.z;
  const u16* Bw = wqkv + (size_t)z * NW;
  const float* bias = z == 0 ? bq : (z == 1 ? bk : bv);
  u16* out = z == 0 ? qo : (z == 1 ? ko : vo);
  const float scale = z == 0 ? 0.125f : 1.0f;
  gemm_body<true>(A, Bw, bias, out, scale, blockIdx.x * 128, blockIdx.y * 128);
}

__global__ __launch_bounds__(256) void gemm_out(const u16* __restrict__ A,
                                                const u16* __restrict__ Bw,
                                                const float* __restrict__ bias,
                                                float* __restrict__ Cp){
  gemm_body<false>(A, Bw, bias, Cp, 1.0f, blockIdx.x * 128, blockIdx.y * 128);
}

// ---------------- V transpose: v[b*S+s][h*64+d] -> vt[(b*H+h)*64+d][s] ----------------
__global__ __launch_bounds__(256) void vt_kernel(const u16* __restrict__ v,
                                                 u16* __restrict__ vt){
  __shared__ __align__(16) u16 tile[64][72];
  const int t = threadIdx.x;
  const int s0 = blockIdx.x * 64;
  const int bh = blockIdx.y;
  const int b = bh / HH, h = bh % HH;
  {
    const int r = t >> 2, c = (t & 3) * 16;
    const u16* src = v + (size_t)(b * SS + s0 + r) * EE + h * DD + c;
    *(s8v*)&tile[r][c]     = *(const s8v*)src;
    *(s8v*)&tile[r][c + 8] = *(const s8v*)(src + 8);
  }
  __syncthreads();
  {
    const int d = t >> 2, sc = (t & 3) * 16;
    s8v o0, o1;
    #pragma unroll
    for (int i = 0; i < 8; i++){
      o0[i] = (short)tile[sc + i][d];
      o1[i] = (short)tile[sc + 8 + i][d];
    }
    u16* dst = vt + (size_t)(bh * DD + d) * SS + s0 + sc;
    *(s8v*)dst       = o0;
    *(s8v*)(dst + 8) = o1;
  }
}

// ---------------- flash attention with gated bias from LDS table ----------------
__global__ __launch_bounds__(256) void attn_kernel(const u16* __restrict__ qb,
                                                   const u16* __restrict__ kb,
                                                   const u16* __restrict__ vtb,
                                                   const float* __restrict__ gate,
                                                   const float* __restrict__ tbl,
                                                   u16* __restrict__ ctx){
  __shared__ __align__(16) u16 q_s[64][72];
  __shared__ __align__(16) u16 k_s[64][72];
  __shared__ __align__(16) u16 v_s[64][72];
  __shared__ __align__(16) u16 p_s[4][16][72];
  __shared__ __align__(16) float tbl_s[2048];
  const int t = threadIdx.x, wave = t >> 6, lane = t & 63;
  const int lr = lane & 15, lg = lane >> 4;
  const int q0 = blockIdx.x * 64;
  const int h = blockIdx.y, b = blockIdx.z;
  const int sr = t >> 2, scc = (t & 3) * 16;
  {
    const u16* src = qb + (size_t)(b * SS + q0 + sr) * EE + h * DD + scc;
    *(s8v*)&q_s[sr][scc]     = *(const s8v*)src;
    *(s8v*)&q_s[sr][scc + 8] = *(const s8v*)(src + 8);
    const float* th = tbl + h * 2048 + t * 8;
    *(f4v*)&tbl_s[t * 8]     = *(const f4v*)th;
    *(f4v*)&tbl_s[t * 8 + 4] = *(const f4v*)(th + 4);
  }
  __syncthreads();
  const s8v qf0 = *(const s8v*)&q_s[wave * 16 + lr][lg * 8];
  const s8v qf1 = *(const s8v*)&q_s[wave * 16 + lr][32 + lg * 8];
  float gt[4];
  #pragma unroll
  for (int r = 0; r < 4; r++)
    gt[r] = gate[(size_t)(b * HH + h) * SS + q0 + wave * 16 + lg * 4 + r];

  const f4v zero = {0.f, 0.f, 0.f, 0.f};
  f4v o[4];
  float m[4], l[4];
  #pragma unroll
  for (int d = 0; d < 4; d++) o[d] = zero;
  #pragma unroll
  for (int r = 0; r < 4; r++){ m[r] = -1e30f; l[r] = 0.f; }

  const u16* kbase = kb + (size_t)b * SS * EE + h * DD;
  const u16* vbase = vtb + (size_t)(b * HH + h) * DD * SS;
  const int qrow = q0 + wave * 16 + lg * 4;

  for (int kt = 0; kt < 16; kt++){
    const int k0 = kt * 64;
    __syncthreads();
    {
      const u16* ks = kbase + (size_t)(k0 + sr) * EE + scc;
      *(s8v*)&k_s[sr][scc]     = *(const s8v*)ks;
      *(s8v*)&k_s[sr][scc + 8] = *(const s8v*)(ks + 8);
      const u16* vs = vbase + (size_t)sr * SS + k0 + scc;
      *(s8v*)&v_s[sr][scc]     = *(const s8v*)vs;
      *(s8v*)&v_s[sr][scc + 8] = *(const s8v*)(vs + 8);
    }
    __syncthreads();
    f4v sf[4];
    #pragma unroll
    for (int n = 0; n < 4; n++){
      const s8v kf0 = *(const s8v*)&k_s[n * 16 + lr][lg * 8];
      const s8v kf1 = *(const s8v*)&k_s[n * 16 + lr][32 + lg * 8];
      f4v z = zero;
      z = __builtin_amdgcn_mfma_f32_16x16x32_bf16(qf0, kf0, z, 0, 0, 0);
      z = __builtin_amdgcn_mfma_f32_16x16x32_bf16(qf1, kf1, z, 0, 0, 0);
      sf[n] = z;
    }
    #pragma unroll
    for (int n = 0; n < 4; n++){
      const int base = k0 + n * 16 + lr - qrow + 1023;
      #pragma unroll
      for (int r = 0; r < 4; r++)
        sf[n][r] += gt[r] * tbl_s[base - r];
    }

    float mx[4], scl[4], rs[4];
    #pragma unroll
    for (int r = 0; r < 4; r++)
      mx[r] = fmaxf(fmaxf(sf[0][r], sf[1][r]), fmaxf(sf[2][r], sf[3][r]));
    #pragma unroll
    for (int off = 1; off < 16; off <<= 1)
      #pragma unroll
      for (int r = 0; r < 4; r++)
        mx[r] = fmaxf(mx[r], __shfl_xor(mx[r], off));
    #pragma unroll
    for (int r = 0; r < 4; r++){
      float nm = fmaxf(m[r], mx[r]);
      scl[r] = __expf(m[r] - nm);
      m[r] = nm;
      rs[r] = 0.f;
    }
    #pragma unroll
    for (int n = 0; n < 4; n++)
      #pragma unroll
      for (int r = 0; r < 4; r++){
        float p = __expf(sf[n][r] - m[r]);
        sf[n][r] = p;
        rs[r] += p;
      }
    #pragma unroll
    for (int off = 1; off < 16; off <<= 1)
      #pragma unroll
      for (int r = 0; r < 4; r++)
        rs[r] += __shfl_xor(rs[r], off);
    #pragma unroll
    for (int r = 0; r < 4; r++)
      l[r] = l[r] * scl[r] + rs[r];
    #pragma unroll
    for (int d = 0; d < 4; d++)
      #pragma unroll
      for (int r = 0; r < 4; r++)
        o[d][r] *= scl[r];
    #pragma unroll
    for (int n = 0; n < 4; n++)
      #pragma unroll
      for (int r = 0; r < 4; r++)
        p_s[wave][lg * 4 + r][n * 16 + lr] = f2bf(sf[n][r]);
    __syncthreads();
    const s8v pf0 = *(const s8v*)&p_s[wave][lr][lg * 8];
    const s8v pf1 = *(const s8v*)&p_s[wave][lr][32 + lg * 8];
    #pragma unroll
    for (int d = 0; d < 4; d++){
      const s8v vf0 = *(const s8v*)&v_s[d * 16 + lr][lg * 8];
      const s8v vf1 = *(const s8v*)&v_s[d * 16 + lr][32 + lg * 8];
      o[d] = __builtin_amdgcn_mfma_f32_16x16x32_bf16(pf0, vf0, o[d], 0, 0, 0);
      o[d] = __builtin_amdgcn_mfma_f32_16x16x32_bf16(pf1, vf1, o[d], 0, 0, 0);
    }
  }
  #pragma unroll
  for (int d = 0; d < 4; d++)
    #pragma unroll
    for (int r = 0; r < 4; r++){
      float val = o[d][r] / l[r];
      ctx[(size_t)(b * SS + qrow + r) * EE + h * DD + d * 16 + lr] = f2bf(val);
    }
}

extern "C" void kernel_launch(void* const* d_in, const int* in_sizes, int n_in,
                              void* d_out, int out_size, void* d_ws, size_t ws_size,
                              hipStream_t stream){
  const float* hs    = (const float*)d_in[0];
  const float* q_w   = (const float*)d_in[1];
  const float* q_b   = (const float*)d_in[2];
  const float* k_w   = (const float*)d_in[3];
  const float* k_b   = (const float*)d_in[4];
  const float* v_w   = (const float*)d_in[5];
  const float* v_b   = (const float*)d_in[6];
  const float* o_w   = (const float*)d_in[7];
  const float* o_b   = (const float*)d_in[8];
  const float* gru_c = (const float*)d_in[9];
  const float* gru_w = (const float*)d_in[10];
  const float* gru_b = (const float*)d_in[11];
  const float* rel   = (const float*)d_in[12];

  float* out0 = (float*)d_out;
  float* pb   = out0 + (size_t)BB * SS * EE;

  char* w = (char*)d_ws;
  u16* qbuf = (u16*)w;  w += (size_t)NHS * 2;     // also ctx (in-place)
  u16* kbuf = (u16*)w;  w += (size_t)NHS * 2;
  u16* vbuf = (u16*)w;  w += (size_t)NHS * 2;
  u16* vtb  = (u16*)w;  w += (size_t)NHS * 2;
  u16* cvt  = (u16*)w;  w += ((size_t)NHS + 4 * (size_t)NW) * 2;
  float* gate = (float*)w; w += (size_t)BB * HH * SS * 4;
  float* tbl  = (float*)w;

  u16* hs_bf  = cvt;
  u16* wqkv   = cvt + NHS;             // q_w, k_w, v_w bf16 packed
  u16* ow_bf  = cvt + NHS + 3 * (size_t)NW;

  cvt_kernel<<<(NHS + 4 * NW) / (256 * 8), 256, 0, stream>>>(hs, q_w, k_w, v_w, o_w, cvt);
  tbl_kernel<<<(HH * 2048) / 256, 256, 0, stream>>>(rel, tbl);
  gate_kernel<<<(BB * HH * SS) / 4, 256, 0, stream>>>(hs, gru_w, gru_b, gru_c, gate);
  pb_kernel<<<(SS * SS / 4) / 256, 256, 0, stream>>>(tbl, pb);
  gemm_qkv<<<dim3(32, 6, 3), 256, 0, stream>>>(hs_bf, wqkv, q_b, k_b, v_b, qbuf, kbuf, vbuf);
  vt_kernel<<<dim3(SS / 64, BB * HH), 256, 0, stream>>>(vbuf, vtb);
  attn_kernel<<<dim3(SS / 64, HH, BB), 256, 0, stream>>>(qbuf, kbuf, vtb, gate, tbl, qbuf);
  gemm_out<<<dim3(32, 6), 256, 0, stream>>>(qbuf, ow_bf, o_b, out0);
}